// Round 1
// baseline (588.109 us; speedup 1.0000x reference)
//
#include <hip/hip_runtime.h>
#include <hip/hip_bf16.h>
#include <math.h>

#define IC 512
#define OC 512
#define STYLE 512
#define BB 8
#define H_ 64
#define W_ 64
#define HW 4096
#define HP 66          // padded rows (zero row above and below)
#define KC 32          // channel chunk per MFMA K-step
#define NCHUNK 16
#define COLSTRIDE 80   // bytes per (row,col) slot in conv LDS (64 data + 16 pad)
#define ROWSTRIDE (66*COLSTRIDE)

typedef __attribute__((ext_vector_type(8))) __bf16 bf16x8;
typedef __attribute__((ext_vector_type(4))) float floatx4;

static __device__ __forceinline__ unsigned short f2bf(float f) {
    unsigned u = __builtin_bit_cast(unsigned, f);
    unsigned r = u + 0x7FFFu + ((u >> 16) & 1u);   // RNE
    return (unsigned short)(r >> 16);
}

// ---------------- K1: s[b,i] = MOD_SCALE * style[b,:]·(mod_weight + fcB@fcA^T)[i,:] + biases
__global__ void k_style(const float* __restrict__ style, const float* __restrict__ mod_weight,
                        const float* __restrict__ mod_bias, const float* __restrict__ fc_lora_A,
                        const float* __restrict__ fc_lora_B, const float* __restrict__ fc_lora_bias,
                        float* __restrict__ s_out) {
    int gid = blockIdx.x * 256 + threadIdx.x;      // 4096
    int b = gid >> 9, i = gid & 511;
    float4 fb = *(const float4*)&fc_lora_B[i * 4];
    const float* st = style + b * STYLE;
    const float* mw = mod_weight + (size_t)i * STYLE;
    float acc = 0.f;
    for (int j = 0; j < STYLE; ++j) {
        float4 fa = *(const float4*)&fc_lora_A[j * 4];
        float w = mw[j] + fb.x * fa.x + fb.y * fa.y + fb.z * fa.z + fb.w * fa.w;
        acc += st[j] * w;
    }
    float mod_scale = 1.0f / sqrtf((float)STYLE);
    s_out[gid] = mod_scale * acc + mod_bias[i] + fc_lora_bias[i];
}

// ---------------- K2: w5 = weight + relu(A·relu(B·inst)); wb[t][o][i] bf16; W2[o][i] = sum_k w5^2
__global__ void k_weight(const float* __restrict__ weight, const float* __restrict__ llB,
                         const float* __restrict__ llBinst, const float* __restrict__ llA,
                         unsigned short* __restrict__ wb, float* __restrict__ W2) {
    int gid = blockIdx.x * 256 + threadIdx.x;      // 262144
    int o = gid >> 9, i = gid & 511;
    float4 vB = *(const float4*)&llB[o * 4];
    float4 vA = *(const float4*)&llA[i * 4];
    const float* wrow = weight + (size_t)(o * IC + i) * 9;
    float w2 = 0.f;
    #pragma unroll
    for (int k = 0; k < 9; ++k) {
        float wadd = 0.f;
        #pragma unroll
        for (int bb = 0; bb < 4; ++bb) {
            float bm = vB.x * llBinst[(bb * 4 + 0) * 9 + k] + vB.y * llBinst[(bb * 4 + 1) * 9 + k]
                     + vB.z * llBinst[(bb * 4 + 2) * 9 + k] + vB.w * llBinst[(bb * 4 + 3) * 9 + k];
            bm = fmaxf(bm, 0.f);
            float a = (bb == 0) ? vA.x : (bb == 1) ? vA.y : (bb == 2) ? vA.z : vA.w;
            wadd += a * bm;
        }
        wadd = fmaxf(wadd, 0.f);
        float w5 = wrow[k] + wadd;                 // LORA_ALPHA_CONV = 1
        wb[(size_t)(k * OC + o) * IC + i] = f2bf(w5);
        w2 += w5 * w5;
    }
    W2[gid] = w2;
}

// ---------------- K3: scale[b][o] = CONV_SCALE * rsqrt(CONV_SCALE^2 * sum_i W2[o,i]*s[b,i]^2 + eps)
__global__ void k_scale(const float* __restrict__ W2, const float* __restrict__ s,
                        float* __restrict__ scale) {
    int gid = blockIdx.x * 256 + threadIdx.x;      // 4096
    int b = gid >> 9, o = gid & 511;
    const float* w2r = W2 + (size_t)o * IC;
    const float* sr = s + b * IC;
    float acc = 0.f;
    for (int i = 0; i < IC; ++i) { float sv = sr[i]; acc += w2r[i] * sv * sv; }
    float cs = 1.0f / sqrtf((float)(IC * 9));
    scale[gid] = cs * rsqrtf(cs * cs * acc + 1e-8f);
}

// ---------------- K4b: zero padded top/bottom rows of xm
__global__ void k_zero_rows(unsigned short* __restrict__ xm) {
    int gid = blockIdx.x * 256 + threadIdx.x;      // 65536 x 16B
    int rowIdx = gid >> 12;                        // 16 zero rows
    int rem = gid & 4095;
    int b = rowIdx >> 1;
    int hp = (rowIdx & 1) ? (HP - 1) : 0;
    uint4 z = make_uint4(0, 0, 0, 0);
    *(uint4*)((char*)(xm + ((size_t)(b * HP + hp) * W_) * IC) + (size_t)rem * 16) = z;
}

// ---------------- K4: xm[b][h+1][w][c] = bf16(x[b][c][h][w] * s[b][c])  (NCHW -> padded NHWC)
__global__ void k_stage_x(const float* __restrict__ x, const float* __restrict__ s,
                          unsigned short* __restrict__ xm) {
    __shared__ float tile[128 * 65];
    int cc = blockIdx.x;   // 0..3
    int h  = blockIdx.y;   // 0..63
    int b  = blockIdx.z;
    int c0 = cc * 128;
    int tid = threadIdx.x;
    const float* xin = x + (((size_t)b * IC + c0) * H_ + h) * W_;
    #pragma unroll
    for (int p = 0; p < 32; ++p) {
        int idx = p * 256 + tid;
        int c = idx >> 6, w = idx & 63;
        tile[c * 65 + w] = xin[(size_t)c * HW + w];
    }
    __syncthreads();
    const float* sb = s + b * IC + c0;
    unsigned short* xr = xm + ((size_t)(b * HP + (h + 1)) * W_) * IC + c0;
    #pragma unroll
    for (int p = 0; p < 16; ++p) {
        int idx = p * 256 + tid;
        int w = idx >> 6, cp = idx & 63;
        int c = cp * 2;
        float v0 = tile[c * 65 + w] * sb[c];
        float v1 = tile[(c + 1) * 65 + w] * sb[c + 1];
        unsigned int u = (unsigned)f2bf(v0) | ((unsigned)f2bf(v1) << 16);
        *(unsigned int*)&xr[(size_t)w * IC + c] = u;
    }
}

// ---------------- K5: conv. block = 64 oc x (4 rows x 64 cols). wave = one output row.
__global__ __launch_bounds__(256) void k_conv(const unsigned short* __restrict__ wb,
                                              const unsigned short* __restrict__ xm,
                                              const float* __restrict__ scale,
                                              float* __restrict__ out) {
    __shared__ unsigned short xs[6 * 66 * (COLSTRIDE / 2)];   // 31680 B
    const int tid = threadIdx.x;
    const int wave = tid >> 6, lane = tid & 63;
    const int l16 = lane & 15, lq = lane >> 4;
    const int ht = blockIdx.x;          // 0..15
    const int ot = blockIdx.y;          // 0..7
    const int b  = blockIdx.z;          // 0..7
    const int om = ot * 64;
    const int h0 = ht * 4;

    // zero border columns pc=0 and pc=65 (data bytes only)
    if (tid < 48) {
        int row = tid >> 3;
        int rem = tid & 7;
        int side = rem >> 2;
        int part = rem & 3;
        uint4 z = make_uint4(0, 0, 0, 0);
        *(uint4*)((char*)xs + row * ROWSTRIDE + side * 65 * COLSTRIDE + part * 16) = z;
    }

    floatx4 acc[4][4];
    #pragma unroll
    for (int mt = 0; mt < 4; ++mt)
        #pragma unroll
        for (int nt = 0; nt < 4; ++nt)
            acc[mt][nt] = (floatx4){0.f, 0.f, 0.f, 0.f};

    const unsigned short* xmb = xm + (size_t)b * HP * W_ * IC;
    const int scol = tid >> 2;          // 0..63 (column)
    const int ssub = (tid & 3) * 8;     // channel sub-offset (elements)
    const unsigned short* wbl = wb + (size_t)(om + l16) * IC + lq * 8;

    // prefetch chunk 0 into registers
    uint4 pre[6];
    #pragma unroll
    for (int j = 0; j < 6; ++j)
        pre[j] = *(const uint4*)(xmb + ((size_t)(h0 + j) * W_ + scol) * IC + ssub);

    for (int ci = 0; ci < NCHUNK; ++ci) {
        __syncthreads();                // previous chunk's readers done
        #pragma unroll
        for (int j = 0; j < 6; ++j)
            *(uint4*)((char*)xs + j * ROWSTRIDE + (scol + 1) * COLSTRIDE + ssub * 2) = pre[j];
        __syncthreads();
        if (ci + 1 < NCHUNK) {          // issue next chunk's global loads before MFMA block
            #pragma unroll
            for (int j = 0; j < 6; ++j)
                pre[j] = *(const uint4*)(xmb + ((size_t)(h0 + j) * W_ + scol) * IC + (ci + 1) * KC + ssub);
        }
        #pragma unroll
        for (int kh = 0; kh < 3; ++kh) {
            #pragma unroll
            for (int dw = 0; dw < 3; ++dw) {
                const int t = kh * 3 + dw;
                bf16x8 af[4], bv[4];
                #pragma unroll
                for (int mt = 0; mt < 4; ++mt)
                    af[mt] = *(const bf16x8*)(wbl + (size_t)t * OC * IC + mt * 16 * IC + ci * KC);
                #pragma unroll
                for (int nt = 0; nt < 4; ++nt)
                    bv[nt] = *(const bf16x8*)((char*)xs + (wave + kh) * ROWSTRIDE
                                              + (nt * 16 + l16 + dw) * COLSTRIDE + lq * 16);
                #pragma unroll
                for (int mt = 0; mt < 4; ++mt)
                    #pragma unroll
                    for (int nt = 0; nt < 4; ++nt)
                        acc[mt][nt] = __builtin_amdgcn_mfma_f32_16x16x32_bf16(af[mt], bv[nt], acc[mt][nt], 0, 0, 0);
            }
        }
    }

    // epilogue: out = acc * (CONV_SCALE * demod)[b][o]
    const int h = h0 + wave;
    float* outb = out + ((size_t)(b * OC + om)) * HW + h * W_;
    const float* scb = scale + b * OC + om;
    #pragma unroll
    for (int mt = 0; mt < 4; ++mt) {
        float4 sc = *(const float4*)&scb[mt * 16 + lq * 4];
        const float* scp = (const float*)&sc;
        #pragma unroll
        for (int nt = 0; nt < 4; ++nt) {
            #pragma unroll
            for (int r = 0; r < 4; ++r)
                outb[(size_t)(mt * 16 + lq * 4 + r) * HW + nt * 16 + l16] = acc[mt][nt][r] * scp[r];
        }
    }
}

extern "C" void kernel_launch(void* const* d_in, const int* in_sizes, int n_in,
                              void* d_out, int out_size, void* d_ws, size_t ws_size,
                              hipStream_t stream) {
    const float* input   = (const float*)d_in[0];
    const float* style   = (const float*)d_in[1];
    const float* weight  = (const float*)d_in[2];
    const float* llB     = (const float*)d_in[3];
    const float* llBinst = (const float*)d_in[4];
    const float* llA     = (const float*)d_in[5];
    const float* mod_w   = (const float*)d_in[6];
    const float* mod_b   = (const float*)d_in[7];
    const float* fcA     = (const float*)d_in[8];
    const float* fcB     = (const float*)d_in[9];
    const float* fcBias  = (const float*)d_in[10];
    float* out = (float*)d_out;

    char* ws = (char*)d_ws;
    float* s_ws            = (float*)(ws + 0);                  // 16 KB
    float* scale_ws        = (float*)(ws + 16384);              // 16 KB
    float* W2_ws           = (float*)(ws + 32768);              // 1 MB
    unsigned short* wb_ws  = (unsigned short*)(ws + 32768 + 1048576);          // 4.72 MB
    unsigned short* xm_ws  = (unsigned short*)(ws + 32768 + 1048576 + 4718592); // 34.6 MB

    k_style<<<16, 256, 0, stream>>>(style, mod_w, mod_b, fcA, fcB, fcBias, s_ws);
    k_weight<<<1024, 256, 0, stream>>>(weight, llB, llBinst, llA, wb_ws, W2_ws);
    k_scale<<<16, 256, 0, stream>>>(W2_ws, s_ws, scale_ws);
    k_zero_rows<<<256, 256, 0, stream>>>(xm_ws);
    k_stage_x<<<dim3(4, 64, 8), 256, 0, stream>>>(input, s_ws, xm_ws);
    k_conv<<<dim3(16, 8, 8), 256, 0, stream>>>(wb_ws, xm_ws, scale_ws, out);
}

// Round 2
// 398.462 us; speedup vs baseline: 1.4759x; 1.4759x over previous
//
#include <hip/hip_runtime.h>
#include <hip/hip_bf16.h>
#include <math.h>

#define IC 512
#define OC 512
#define STYLE 512
#define BB 8
#define H_ 64
#define W_ 64
#define HW 4096
#define HP 66          // padded rows (zero row above and below)
#define KC 32          // channel chunk per MFMA K-step
#define NCHUNK 16
#define USTRIDE 1056   // bytes per u-granule plane in conv LDS: 66 cols * 16B
#define ROWSTRIDE 4224 // 4 * USTRIDE

typedef __attribute__((ext_vector_type(8))) __bf16 bf16x8;
typedef __attribute__((ext_vector_type(4))) float floatx4;

static __device__ __forceinline__ unsigned short f2bf(float f) {
    unsigned u = __builtin_bit_cast(unsigned, f);
    unsigned r = u + 0x7FFFu + ((u >> 16) & 1u);   // RNE
    return (unsigned short)(r >> 16);
}

// ---------------- K1: s[b,i] = MOD_SCALE * style[b,:]·(mod_weight + fcB@fcA^T)[i,:] + biases
// grid (32, 8): block = (i-chunk of 16, b). thread = (i_local 0..15, jg 0..15), 32 j's each.
__global__ void k_style(const float* __restrict__ style, const float* __restrict__ mod_weight,
                        const float* __restrict__ mod_bias, const float* __restrict__ fc_lora_A,
                        const float* __restrict__ fc_lora_B, const float* __restrict__ fc_lora_bias,
                        float* __restrict__ s_out) {
    int b = blockIdx.y;
    int i = blockIdx.x * 16 + (threadIdx.x >> 4);
    int jg = threadIdx.x & 15;
    float4 fb = *(const float4*)&fc_lora_B[i * 4];
    const float* st = style + b * STYLE;
    const float* mw = mod_weight + (size_t)i * STYLE;
    float acc = 0.f;
    for (int j = jg * 32; j < jg * 32 + 32; ++j) {
        float4 fa = *(const float4*)&fc_lora_A[j * 4];
        float w = mw[j] + fb.x * fa.x + fb.y * fa.y + fb.z * fa.z + fb.w * fa.w;
        acc += st[j] * w;
    }
    #pragma unroll
    for (int off = 8; off; off >>= 1) acc += __shfl_down(acc, off, 16);
    if (jg == 0) {
        float mod_scale = 1.0f / sqrtf((float)STYLE);
        s_out[b * IC + i] = mod_scale * acc + mod_bias[i] + fc_lora_bias[i];
    }
}

// ---------------- K2: w5 = weight + relu(A·relu(B·inst)); wb swizzled for MFMA A-frags; W2[o][i]
// wb layout: [t(9)][ot(8)][mt(4)][ci(16)][lane(64)][8]  (lane = lq*16 + l16; o = ot*64+mt*16+l16;
//            channel i = ci*32 + lq*8 + sub)
__global__ void k_weight(const float* __restrict__ weight, const float* __restrict__ llB,
                         const float* __restrict__ llBinst, const float* __restrict__ llA,
                         unsigned short* __restrict__ wb, float* __restrict__ W2) {
    int gid = blockIdx.x * 256 + threadIdx.x;      // 262144
    int o = gid >> 9, i = gid & 511;
    float4 vB = *(const float4*)&llB[o * 4];
    float4 vA = *(const float4*)&llA[i * 4];
    const float* wrow = weight + (size_t)(o * IC + i) * 9;
    int lane = ((i >> 3) & 3) * 16 + (o & 15);
    size_t wbase = (((size_t)((o >> 6) * 4 + ((o >> 4) & 3)) * 16 + (i >> 5)) * 64 + lane) * 8 + (i & 7);
    float w2 = 0.f;
    #pragma unroll
    for (int k = 0; k < 9; ++k) {
        float wadd = 0.f;
        #pragma unroll
        for (int bb = 0; bb < 4; ++bb) {
            float bm = vB.x * llBinst[(bb * 4 + 0) * 9 + k] + vB.y * llBinst[(bb * 4 + 1) * 9 + k]
                     + vB.z * llBinst[(bb * 4 + 2) * 9 + k] + vB.w * llBinst[(bb * 4 + 3) * 9 + k];
            bm = fmaxf(bm, 0.f);
            float a = (bb == 0) ? vA.x : (bb == 1) ? vA.y : (bb == 2) ? vA.z : vA.w;
            wadd += a * bm;
        }
        wadd = fmaxf(wadd, 0.f);
        float w5 = wrow[k] + wadd;                 // LORA_ALPHA_CONV = 1
        wb[(size_t)k * 262144 + wbase] = f2bf(w5);
        w2 += w5 * w5;
    }
    W2[gid] = w2;
}

// ---------------- K3: scale[b][o] = CONV_SCALE * rsqrt(CONV_SCALE^2 * sum_i W2[o,i]*s[b,i]^2 + eps)
// grid (32, 8): block = (o-chunk of 16, b)
__global__ void k_scale(const float* __restrict__ W2, const float* __restrict__ s,
                        float* __restrict__ scale) {
    int b = blockIdx.y;
    int o = blockIdx.x * 16 + (threadIdx.x >> 4);
    int jg = threadIdx.x & 15;
    const float* w2r = W2 + (size_t)o * IC;
    const float* sr = s + b * IC;
    float acc = 0.f;
    for (int i = jg * 32; i < jg * 32 + 32; ++i) { float sv = sr[i]; acc += w2r[i] * sv * sv; }
    #pragma unroll
    for (int off = 8; off; off >>= 1) acc += __shfl_down(acc, off, 16);
    if (jg == 0) {
        float cs = 1.0f / sqrtf((float)(IC * 9));
        scale[b * OC + o] = cs * rsqrtf(cs * cs * acc + 1e-8f);
    }
}

// ---------------- K4b: zero padded top/bottom rows of xm (row = 32768 elems regardless of layout)
__global__ void k_zero_rows(unsigned short* __restrict__ xm) {
    int gid = blockIdx.x * 256 + threadIdx.x;      // 65536 x 16B
    int rowIdx = gid >> 12;                        // 16 zero rows
    int rem = gid & 4095;
    int b = rowIdx >> 1;
    int hp = (rowIdx & 1) ? (HP - 1) : 0;
    uint4 z = make_uint4(0, 0, 0, 0);
    *(uint4*)((char*)(xm + (size_t)(b * HP + hp) * 32768) + (size_t)rem * 16) = z;
}

// ---------------- K4: NCHW fp32 -> xm[b][hp][ci(16)][u(4)][w(64)][8ch] bf16, modulated by s
__global__ void k_stage_x(const float* __restrict__ x, const float* __restrict__ s,
                          unsigned short* __restrict__ xm) {
    __shared__ float tile[128 * 65];
    int cc = blockIdx.x;   // 0..3 (128-channel chunk)
    int h  = blockIdx.y;   // 0..63
    int b  = blockIdx.z;
    int c0 = cc * 128;
    int tid = threadIdx.x;
    const float* xin = x + (((size_t)b * IC + c0) * H_ + h) * W_;
    #pragma unroll
    for (int p = 0; p < 32; ++p) {
        int idx = p * 256 + tid;
        int c = idx >> 6, w = idx & 63;
        tile[c * 65 + w] = xin[(size_t)c * HW + w];
    }
    __syncthreads();
    const float* sb = s + b * IC + c0;
    #pragma unroll
    for (int p = 0; p < 4; ++p) {
        int idx = p * 256 + tid;               // 0..1023
        int cil = idx >> 8;                    // local ci 0..3
        int u   = (idx >> 6) & 3;
        int w   = idx & 63;
        int cb  = cil * 32 + u * 8;
        unsigned int packed[4];
        #pragma unroll
        for (int k = 0; k < 4; ++k) {
            unsigned lo = f2bf(tile[(cb + 2 * k) * 65 + w] * sb[cb + 2 * k]);
            unsigned hi = f2bf(tile[(cb + 2 * k + 1) * 65 + w] * sb[cb + 2 * k + 1]);
            packed[k] = lo | (hi << 16);
        }
        size_t g = (((size_t)(b * HP + h + 1) * 16 + (cc * 4 + cil)) * 4 + u) * 64 + w;
        *(uint4*)(xm + g * 8) = make_uint4(packed[0], packed[1], packed[2], packed[3]);
    }
}

// ---------------- K5: conv. block = 64 oc x (4 rows x 64 cols). wave = one output row.
__global__ __launch_bounds__(256) void k_conv(const unsigned short* __restrict__ wb,
                                              const unsigned short* __restrict__ xm,
                                              const float* __restrict__ scale,
                                              float* __restrict__ out) {
    __shared__ unsigned char xs[6 * ROWSTRIDE];    // 25344 B; epilogue reuses (17408 B)
    const int tid = threadIdx.x;
    const int wave = tid >> 6, lane = tid & 63;
    const int l16 = lane & 15, lq = lane >> 4;
    const int ht = blockIdx.x;          // 0..15
    const int ot = blockIdx.y;          // 0..7
    const int b  = blockIdx.z;          // 0..7
    const int om = ot * 64;
    const int h0 = ht * 4;

    // zero border col-granules (cols 0 and 65, all rows, all u): 6*4*2 = 48 x 16B
    if (tid < 48) {
        int row = tid >> 3;
        int rem = tid & 7;
        int u = rem >> 1;
        int side = rem & 1;
        uint4 z = make_uint4(0, 0, 0, 0);
        *(uint4*)(xs + row * ROWSTRIDE + u * USTRIDE + side * 65 * 16) = z;
    }

    floatx4 acc[4][4];
    #pragma unroll
    for (int mt = 0; mt < 4; ++mt)
        #pragma unroll
        for (int nt = 0; nt < 4; ++nt)
            acc[mt][nt] = (floatx4){0.f, 0.f, 0.f, 0.f};

    // x staging: wave `wave` handles channel-granule u=wave, all 64 cols (lane=col) -> 1KB coalesced
    const unsigned short* xmb = xm + (size_t)b * HP * 32768;
    // weights: swizzled so per-wave load is base + lane*16B (coalesced)
    const unsigned short* wlb = wb + (size_t)ot * 32768 + (size_t)lane * 8;

    // prefetch chunk 0 into registers
    uint4 pre[6];
    #pragma unroll
    for (int j = 0; j < 6; ++j)
        pre[j] = *(const uint4*)(xmb + ((((size_t)(h0 + j) * 16 + 0) * 4 + wave) * 64 + lane) * 8);

    for (int ci = 0; ci < NCHUNK; ++ci) {
        __syncthreads();                // previous chunk's readers done
        #pragma unroll
        for (int j = 0; j < 6; ++j)
            *(uint4*)(xs + (size_t)j * ROWSTRIDE + wave * USTRIDE + (lane + 1) * 16) = pre[j];
        __syncthreads();
        if (ci + 1 < NCHUNK) {          // issue next chunk's global loads before MFMA block
            #pragma unroll
            for (int j = 0; j < 6; ++j)
                pre[j] = *(const uint4*)(xmb + ((((size_t)(h0 + j) * 16 + (ci + 1)) * 4 + wave) * 64 + lane) * 8);
        }
        const unsigned short* wlc = wlb + (size_t)ci * 512;
        #pragma unroll
        for (int kh = 0; kh < 3; ++kh) {
            #pragma unroll
            for (int dw = 0; dw < 3; ++dw) {
                const int t = kh * 3 + dw;
                bf16x8 af[4], bv[4];
                #pragma unroll
                for (int mt = 0; mt < 4; ++mt)
                    af[mt] = *(const bf16x8*)(wlc + (size_t)t * 262144 + mt * 8192);
                #pragma unroll
                for (int nt = 0; nt < 4; ++nt)
                    bv[nt] = *(const bf16x8*)(xs + (size_t)(wave + kh) * ROWSTRIDE + lq * USTRIDE
                                              + (nt * 16 + l16 + dw) * 16);
                #pragma unroll
                for (int mt = 0; mt < 4; ++mt)
                    #pragma unroll
                    for (int nt = 0; nt < 4; ++nt)
                        acc[mt][nt] = __builtin_amdgcn_mfma_f32_16x16x32_bf16(af[mt], bv[nt], acc[mt][nt], 0, 0, 0);
            }
        }
    }

    // ---- epilogue: scale, then stage through LDS for fully-coalesced float4 stores
    __syncthreads();                    // xs x-tile no longer needed by any wave
    float* ebuf = (float*)xs + wave * 1088;        // 16 rows x 68 floats per wave
    const int h = h0 + wave;
    const float* scb = scale + b * OC + om;
    #pragma unroll
    for (int mt = 0; mt < 4; ++mt) {
        float4 sc = *(const float4*)&scb[mt * 16 + lq * 4];
        const float* scp = (const float*)&sc;
        #pragma unroll
        for (int nt = 0; nt < 4; ++nt)
            #pragma unroll
            for (int r = 0; r < 4; ++r)
                ebuf[(lq * 4 + r) * 68 + nt * 16 + l16] = acc[mt][nt][r] * scp[r];
        __syncthreads();                // uniform; guarantees write->read ordering
        #pragma unroll
        for (int q = 0; q < 4; ++q) {
            int r0 = q * 4 + (lane >> 4);
            int c0 = (lane & 15) * 4;
            float4 v = *(float4*)&ebuf[r0 * 68 + c0];
            *(float4*)&out[((size_t)(b * OC + om + mt * 16 + r0)) * HW + h * W_ + c0] = v;
        }
        __syncthreads();                // reads done before next mt's writes
    }
}

extern "C" void kernel_launch(void* const* d_in, const int* in_sizes, int n_in,
                              void* d_out, int out_size, void* d_ws, size_t ws_size,
                              hipStream_t stream) {
    const float* input   = (const float*)d_in[0];
    const float* style   = (const float*)d_in[1];
    const float* weight  = (const float*)d_in[2];
    const float* llB     = (const float*)d_in[3];
    const float* llBinst = (const float*)d_in[4];
    const float* llA     = (const float*)d_in[5];
    const float* mod_w   = (const float*)d_in[6];
    const float* mod_b   = (const float*)d_in[7];
    const float* fcA     = (const float*)d_in[8];
    const float* fcB     = (const float*)d_in[9];
    const float* fcBias  = (const float*)d_in[10];
    float* out = (float*)d_out;

    char* ws = (char*)d_ws;
    float* s_ws            = (float*)(ws + 0);                  // 16 KB
    float* scale_ws        = (float*)(ws + 16384);              // 16 KB
    float* W2_ws           = (float*)(ws + 32768);              // 1 MB
    unsigned short* wb_ws  = (unsigned short*)(ws + 32768 + 1048576);          // 4.72 MB
    unsigned short* xm_ws  = (unsigned short*)(ws + 32768 + 1048576 + 4718592); // 34.6 MB

    k_style<<<dim3(32, 8), 256, 0, stream>>>(style, mod_w, mod_b, fcA, fcB, fcBias, s_ws);
    k_weight<<<1024, 256, 0, stream>>>(weight, llB, llBinst, llA, wb_ws, W2_ws);
    k_scale<<<dim3(32, 8), 256, 0, stream>>>(W2_ws, s_ws, scale_ws);
    k_zero_rows<<<256, 256, 0, stream>>>(xm_ws);
    k_stage_x<<<dim3(4, 64, 8), 256, 0, stream>>>(input, s_ws, xm_ws);
    k_conv<<<dim3(16, 8, 8), 256, 0, stream>>>(wb_ws, xm_ws, scale_ws, out);
}

// Round 3
// 396.458 us; speedup vs baseline: 1.4834x; 1.0051x over previous
//
#include <hip/hip_runtime.h>
#include <hip/hip_bf16.h>
#include <math.h>

#define IC 512
#define OC 512
#define STYLE 512
#define BB 8
#define H_ 64
#define W_ 64
#define HW 4096
#define HP 66          // padded rows (zero row above and below)
#define KC 32          // channel chunk per MFMA K-step
#define NCHUNK 16
#define USTRIDE 1056   // bytes per u-granule plane in conv LDS: 66 cols * 16B
#define ROWSTRIDE 4224 // 4 * USTRIDE
#define BUFSZ (6 * ROWSTRIDE)   // 25344 B per x buffer

typedef __attribute__((ext_vector_type(8))) __bf16 bf16x8;
typedef __attribute__((ext_vector_type(4))) float floatx4;

static __device__ __forceinline__ unsigned short f2bf(float f) {
    unsigned u = __builtin_bit_cast(unsigned, f);
    unsigned r = u + 0x7FFFu + ((u >> 16) & 1u);   // RNE
    return (unsigned short)(r >> 16);
}

// ---------------- K1: s[b,i] = MOD_SCALE * style[b,:]·(mod_weight + fcB@fcA^T)[i,:] + biases
// grid (32, 8): block = (i-chunk of 16, b). thread = (i_local 0..15, jg 0..15), 32 j's each.
__global__ void k_style(const float* __restrict__ style, const float* __restrict__ mod_weight,
                        const float* __restrict__ mod_bias, const float* __restrict__ fc_lora_A,
                        const float* __restrict__ fc_lora_B, const float* __restrict__ fc_lora_bias,
                        float* __restrict__ s_out) {
    int b = blockIdx.y;
    int i = blockIdx.x * 16 + (threadIdx.x >> 4);
    int jg = threadIdx.x & 15;
    float4 fb = *(const float4*)&fc_lora_B[i * 4];
    const float* st = style + b * STYLE;
    const float* mw = mod_weight + (size_t)i * STYLE;
    float acc = 0.f;
    for (int j = jg * 32; j < jg * 32 + 32; ++j) {
        float4 fa = *(const float4*)&fc_lora_A[j * 4];
        float w = mw[j] + fb.x * fa.x + fb.y * fa.y + fb.z * fa.z + fb.w * fa.w;
        acc += st[j] * w;
    }
    #pragma unroll
    for (int off = 8; off; off >>= 1) acc += __shfl_down(acc, off, 16);
    if (jg == 0) {
        float mod_scale = 1.0f / sqrtf((float)STYLE);
        s_out[b * IC + i] = mod_scale * acc + mod_bias[i] + fc_lora_bias[i];
    }
}

// ---------------- K2: w5 = weight + relu(A·relu(B·inst)); wb swizzled for MFMA A-frags; W2[o][i]
// wb layout: [t(9)][ot(8)][mt(4)][ci(16)][lane(64)][8]  (lane = lq*16 + l16; o = ot*64+mt*16+l16;
//            channel i = ci*32 + lq*8 + sub)
__global__ void k_weight(const float* __restrict__ weight, const float* __restrict__ llB,
                         const float* __restrict__ llBinst, const float* __restrict__ llA,
                         unsigned short* __restrict__ wb, float* __restrict__ W2) {
    int gid = blockIdx.x * 256 + threadIdx.x;      // 262144
    int o = gid >> 9, i = gid & 511;
    float4 vB = *(const float4*)&llB[o * 4];
    float4 vA = *(const float4*)&llA[i * 4];
    const float* wrow = weight + (size_t)(o * IC + i) * 9;
    int lane = ((i >> 3) & 3) * 16 + (o & 15);
    size_t wbase = (((size_t)((o >> 6) * 4 + ((o >> 4) & 3)) * 16 + (i >> 5)) * 64 + lane) * 8 + (i & 7);
    float w2 = 0.f;
    #pragma unroll
    for (int k = 0; k < 9; ++k) {
        float wadd = 0.f;
        #pragma unroll
        for (int bb = 0; bb < 4; ++bb) {
            float bm = vB.x * llBinst[(bb * 4 + 0) * 9 + k] + vB.y * llBinst[(bb * 4 + 1) * 9 + k]
                     + vB.z * llBinst[(bb * 4 + 2) * 9 + k] + vB.w * llBinst[(bb * 4 + 3) * 9 + k];
            bm = fmaxf(bm, 0.f);
            float a = (bb == 0) ? vA.x : (bb == 1) ? vA.y : (bb == 2) ? vA.z : vA.w;
            wadd += a * bm;
        }
        wadd = fmaxf(wadd, 0.f);
        float w5 = wrow[k] + wadd;                 // LORA_ALPHA_CONV = 1
        wb[(size_t)k * 262144 + wbase] = f2bf(w5);
        w2 += w5 * w5;
    }
    W2[gid] = w2;
}

// ---------------- K3: scale[b][o] = CONV_SCALE * rsqrt(CONV_SCALE^2 * sum_i W2[o,i]*s[b,i]^2 + eps)
// grid (32, 8): block = (o-chunk of 16, b)
__global__ void k_scale(const float* __restrict__ W2, const float* __restrict__ s,
                        float* __restrict__ scale) {
    int b = blockIdx.y;
    int o = blockIdx.x * 16 + (threadIdx.x >> 4);
    int jg = threadIdx.x & 15;
    const float* w2r = W2 + (size_t)o * IC;
    const float* sr = s + b * IC;
    float acc = 0.f;
    for (int i = jg * 32; i < jg * 32 + 32; ++i) { float sv = sr[i]; acc += w2r[i] * sv * sv; }
    #pragma unroll
    for (int off = 8; off; off >>= 1) acc += __shfl_down(acc, off, 16);
    if (jg == 0) {
        float cs = 1.0f / sqrtf((float)(IC * 9));
        scale[b * OC + o] = cs * rsqrtf(cs * cs * acc + 1e-8f);
    }
}

// ---------------- K4: NCHW fp32 -> xm[b][hp][ci(16)][u(4)][w(64)][8ch] bf16, modulated by s
// grid (4, 66, 8): hp = blockIdx.y; hp==0/65 write zeros (padding rows), else stage row hp-1.
__global__ void k_stage_x(const float* __restrict__ x, const float* __restrict__ s,
                          unsigned short* __restrict__ xm) {
    __shared__ float tile[128 * 65];
    int cc = blockIdx.x;   // 0..3 (128-channel chunk)
    int hp = blockIdx.y;   // 0..65
    int b  = blockIdx.z;
    int c0 = cc * 128;
    int tid = threadIdx.x;
    if (hp == 0 || hp == HP - 1) {
        // zero this (b, hp, cc) slice: 4 ci-groups * 4 u * 64 w * 8 ch = 8192 shorts = 16 KB
        unsigned short* dst = xm + (size_t)(b * HP + hp) * 32768 + cc * 8192;
        uint4 z = make_uint4(0, 0, 0, 0);
        #pragma unroll
        for (int p = 0; p < 4; ++p)
            *(uint4*)(dst + (size_t)(p * 256 + tid) * 8) = z;
        return;
    }
    int h = hp - 1;
    const float* xin = x + (((size_t)b * IC + c0) * H_ + h) * W_;
    #pragma unroll
    for (int p = 0; p < 32; ++p) {
        int idx = p * 256 + tid;
        int c = idx >> 6, w = idx & 63;
        tile[c * 65 + w] = xin[(size_t)c * HW + w];
    }
    __syncthreads();
    const float* sb = s + b * IC + c0;
    #pragma unroll
    for (int p = 0; p < 4; ++p) {
        int idx = p * 256 + tid;               // 0..1023
        int cil = idx >> 8;                    // local ci 0..3
        int u   = (idx >> 6) & 3;
        int w   = idx & 63;
        int cb  = cil * 32 + u * 8;
        unsigned int packed[4];
        #pragma unroll
        for (int k = 0; k < 4; ++k) {
            unsigned lo = f2bf(tile[(cb + 2 * k) * 65 + w] * sb[cb + 2 * k]);
            unsigned hi = f2bf(tile[(cb + 2 * k + 1) * 65 + w] * sb[cb + 2 * k + 1]);
            packed[k] = lo | (hi << 16);
        }
        size_t g = (((size_t)(b * HP + hp) * 16 + (cc * 4 + cil)) * 4 + u) * 64 + w;
        *(uint4*)(xm + g * 8) = make_uint4(packed[0], packed[1], packed[2], packed[3]);
    }
}

// ---------------- K5: conv. block = 64 oc x (4 rows x 64 cols). wave = one output row.
// Double-buffered x LDS: one barrier per K-chunk.
__global__ __launch_bounds__(256, 3) void k_conv(const unsigned short* __restrict__ wb,
                                                 const unsigned short* __restrict__ xm,
                                                 const float* __restrict__ scale,
                                                 float* __restrict__ out) {
    __shared__ unsigned char xs[2 * BUFSZ];        // 50688 B; epilogue reuses (17408 B)
    const int tid = threadIdx.x;
    const int wave = tid >> 6, lane = tid & 63;
    const int l16 = lane & 15, lq = lane >> 4;
    const int ht = blockIdx.x;          // 0..15
    const int ot = blockIdx.y;          // 0..7
    const int b  = blockIdx.z;          // 0..7
    const int om = ot * 64;
    const int h0 = ht * 4;

    // zero border col-granules (cols 0 and 65, all 6 rows, all u, BOTH buffers): 96 x 16B
    if (tid < 96) {
        int bsel = tid >= 48;
        int t48 = tid - bsel * 48;
        int row = t48 >> 3;
        int rem = t48 & 7;
        int u = rem >> 1;
        int side = rem & 1;
        uint4 z = make_uint4(0, 0, 0, 0);
        *(uint4*)(xs + bsel * BUFSZ + row * ROWSTRIDE + u * USTRIDE + side * 65 * 16) = z;
    }

    floatx4 acc[4][4];
    #pragma unroll
    for (int mt = 0; mt < 4; ++mt)
        #pragma unroll
        for (int nt = 0; nt < 4; ++nt)
            acc[mt][nt] = (floatx4){0.f, 0.f, 0.f, 0.f};

    // x staging: wave `wave` handles channel-granule u=wave, all 64 cols (lane=col) -> 1KB coalesced
    const unsigned short* xmb = xm + (size_t)b * HP * 32768;
    // weights: swizzled so per-wave load is base + lane*16B (coalesced)
    const unsigned short* wlb = wb + (size_t)ot * 32768 + (size_t)lane * 8;

    // prefetch chunk 0 into registers
    uint4 pre[6];
    #pragma unroll
    for (int j = 0; j < 6; ++j)
        pre[j] = *(const uint4*)(xmb + ((((size_t)(h0 + j) * 16 + 0) * 4 + wave) * 64 + lane) * 8);

    for (int ci = 0; ci < NCHUNK; ++ci) {
        unsigned char* buf = xs + (ci & 1) * BUFSZ;
        #pragma unroll
        for (int j = 0; j < 6; ++j)
            *(uint4*)(buf + (size_t)j * ROWSTRIDE + wave * USTRIDE + (lane + 1) * 16) = pre[j];
        if (ci + 1 < NCHUNK) {          // issue next chunk's global loads before the barrier
            #pragma unroll
            for (int j = 0; j < 6; ++j)
                pre[j] = *(const uint4*)(xmb + ((((size_t)(h0 + j) * 16 + (ci + 1)) * 4 + wave) * 64 + lane) * 8);
        }
        __syncthreads();                // buf now fully staged; prior chunk used the other buffer
        const unsigned short* wlc = wlb + (size_t)ci * 512;
        #pragma unroll
        for (int kh = 0; kh < 3; ++kh) {
            #pragma unroll
            for (int dw = 0; dw < 3; ++dw) {
                const int t = kh * 3 + dw;
                bf16x8 af[4], bv[4];
                #pragma unroll
                for (int mt = 0; mt < 4; ++mt)
                    af[mt] = *(const bf16x8*)(wlc + (size_t)t * 262144 + mt * 8192);
                #pragma unroll
                for (int nt = 0; nt < 4; ++nt)
                    bv[nt] = *(const bf16x8*)(buf + (size_t)(wave + kh) * ROWSTRIDE + lq * USTRIDE
                                              + (nt * 16 + l16 + dw) * 16);
                #pragma unroll
                for (int mt = 0; mt < 4; ++mt)
                    #pragma unroll
                    for (int nt = 0; nt < 4; ++nt)
                        acc[mt][nt] = __builtin_amdgcn_mfma_f32_16x16x32_bf16(af[mt], bv[nt], acc[mt][nt], 0, 0, 0);
            }
        }
    }

    // ---- epilogue: scale, then stage through LDS for fully-coalesced float4 stores
    __syncthreads();                    // all waves done with both x buffers
    float* ebuf = (float*)xs + wave * 1088;        // 16 rows x 68 floats per wave
    const int h = h0 + wave;
    const float* scb = scale + b * OC + om;
    #pragma unroll
    for (int mt = 0; mt < 4; ++mt) {
        float4 sc = *(const float4*)&scb[mt * 16 + lq * 4];
        const float* scp = (const float*)&sc;
        #pragma unroll
        for (int nt = 0; nt < 4; ++nt)
            #pragma unroll
            for (int r = 0; r < 4; ++r)
                ebuf[(lq * 4 + r) * 68 + nt * 16 + l16] = acc[mt][nt][r] * scp[r];
        __syncthreads();                // uniform; guarantees write->read ordering
        #pragma unroll
        for (int q = 0; q < 4; ++q) {
            int r0 = q * 4 + (lane >> 4);
            int c0 = (lane & 15) * 4;
            float4 v = *(float4*)&ebuf[r0 * 68 + c0];
            *(float4*)&out[((size_t)(b * OC + om + mt * 16 + r0)) * HW + h * W_ + c0] = v;
        }
        __syncthreads();                // reads done before next mt's writes
    }
}

extern "C" void kernel_launch(void* const* d_in, const int* in_sizes, int n_in,
                              void* d_out, int out_size, void* d_ws, size_t ws_size,
                              hipStream_t stream) {
    const float* input   = (const float*)d_in[0];
    const float* style   = (const float*)d_in[1];
    const float* weight  = (const float*)d_in[2];
    const float* llB     = (const float*)d_in[3];
    const float* llBinst = (const float*)d_in[4];
    const float* llA     = (const float*)d_in[5];
    const float* mod_w   = (const float*)d_in[6];
    const float* mod_b   = (const float*)d_in[7];
    const float* fcA     = (const float*)d_in[8];
    const float* fcB     = (const float*)d_in[9];
    const float* fcBias  = (const float*)d_in[10];
    float* out = (float*)d_out;

    char* ws = (char*)d_ws;
    float* s_ws            = (float*)(ws + 0);                  // 16 KB
    float* scale_ws        = (float*)(ws + 16384);              // 16 KB
    float* W2_ws           = (float*)(ws + 32768);              // 1 MB
    unsigned short* wb_ws  = (unsigned short*)(ws + 32768 + 1048576);          // 4.72 MB
    unsigned short* xm_ws  = (unsigned short*)(ws + 32768 + 1048576 + 4718592); // 34.6 MB

    k_style<<<dim3(32, 8), 256, 0, stream>>>(style, mod_w, mod_b, fcA, fcB, fcBias, s_ws);
    k_weight<<<1024, 256, 0, stream>>>(weight, llB, llBinst, llA, wb_ws, W2_ws);
    k_scale<<<dim3(32, 8), 256, 0, stream>>>(W2_ws, s_ws, scale_ws);
    k_stage_x<<<dim3(4, 66, 8), 256, 0, stream>>>(input, s_ws, xm_ws);
    k_conv<<<dim3(16, 8, 8), 256, 0, stream>>>(wb_ws, xm_ws, scale_ws, out);
}